// Round 1
// baseline (606.385 us; speedup 1.0000x reference)
//
#include <hip/hip_runtime.h>
#include <hip/hip_bf16.h>
#include <math.h>

typedef short short8 __attribute__((ext_vector_type(8)));
typedef float f32x4 __attribute__((ext_vector_type(4)));
typedef __hip_bfloat16 bf16;

// problem constants
#define KN 10
#define KC 512
#define KHW 1600
#define KH 40
#define KOC 128
#define KPW 42   // padded spatial (40+2)

// ---------------- block reduction helpers (fp64) ----------------
__device__ __forceinline__ double blockReduceSumD(double v) {
  __shared__ double tmpS[8];
  int lane = threadIdx.x & 63, wv = threadIdx.x >> 6;
  #pragma unroll
  for (int o = 32; o > 0; o >>= 1) v += __shfl_down(v, o);
  if (lane == 0) tmpS[wv] = v;
  __syncthreads();
  if (threadIdx.x == 0) {
    int nw = (blockDim.x + 63) >> 6;
    double s = 0;
    for (int i = 0; i < nw; i++) s += tmpS[i];
    tmpS[0] = s;
  }
  __syncthreads();
  double r = tmpS[0];
  __syncthreads();
  return r;
}

__device__ __forceinline__ double blockReduceMinD(double v) {
  __shared__ double tmpMn[8];
  int lane = threadIdx.x & 63, wv = threadIdx.x >> 6;
  #pragma unroll
  for (int o = 32; o > 0; o >>= 1) v = fmin(v, __shfl_down(v, o));
  if (lane == 0) tmpMn[wv] = v;
  __syncthreads();
  if (threadIdx.x == 0) {
    int nw = (blockDim.x + 63) >> 6;
    double s = tmpMn[0];
    for (int i = 1; i < nw; i++) s = fmin(s, tmpMn[i]);
    tmpMn[0] = s;
  }
  __syncthreads();
  double r = tmpMn[0];
  __syncthreads();
  return r;
}

__device__ __forceinline__ double blockReduceMaxD(double v) {
  __shared__ double tmpMx[8];
  int lane = threadIdx.x & 63, wv = threadIdx.x >> 6;
  #pragma unroll
  for (int o = 32; o > 0; o >>= 1) v = fmax(v, __shfl_down(v, o));
  if (lane == 0) tmpMx[wv] = v;
  __syncthreads();
  if (threadIdx.x == 0) {
    int nw = (blockDim.x + 63) >> 6;
    double s = tmpMx[0];
    for (int i = 1; i < nw; i++) s = fmax(s, tmpMx[i]);
    tmpMx[0] = s;
  }
  __syncthreads();
  double r = tmpMx[0];
  __syncthreads();
  return r;
}

// ---------------- small chain (fp64 for argsort stability) ----------------

// rnorm[n,k] = 1 / max(||feats[n,:,k]||_2, 1e-12)
__global__ void k_rnorm(const float* __restrict__ feats, double* __restrict__ rnorm) {
  int t = blockIdx.x * 256 + threadIdx.x;
  if (t >= KN * KHW) return;
  int n = t / KHW, k = t % KHW;
  const float* p = feats + (size_t)n * KC * KHW + k;
  double s = 0.0;
  for (int c = 0; c < KC; ++c) { double v = p[(size_t)c * KHW]; s += v * v; }
  double nn = sqrt(s);
  if (nn < 1e-12) nn = 1e-12;
  rnorm[t] = 1.0 / nn;
}

// NFT[n,k,c] = bf16(feats[n,c,k] * rnorm[n,k])   (transposed, bf16 for MFMA)
__global__ void k_nft(const float* __restrict__ feats, const double* __restrict__ rnorm,
                      bf16* __restrict__ NFT) {
  __shared__ float T[32][33];
  int n = blockIdx.z, k0 = blockIdx.x * 32, c0 = blockIdx.y * 32;
  int tx = threadIdx.x, ty = threadIdx.y;
  const float* fb = feats + ((size_t)n * KC + c0) * KHW + k0;
  #pragma unroll
  for (int ii = 0; ii < 4; ii++) {
    int cl = ty * 4 + ii;
    T[cl][tx] = fb[(size_t)cl * KHW + tx];
  }
  __syncthreads();
  bf16* ob = NFT + ((size_t)n * KHW + k0) * KC + c0;
  #pragma unroll
  for (int ii = 0; ii < 4; ii++) {
    int kl = ty * 4 + ii;
    float r = (float)rnorm[n * KHW + k0 + kl];
    ob[(size_t)kl * KC + tx] = __float2bfloat16(T[tx][kl] * r);
  }
}

// vbuf[n,c] = mean_k( NF[n,c,k] * SISM[n,k] )
__global__ void k_sivpre(const float* __restrict__ feats, const float* __restrict__ sism,
                         const double* __restrict__ rnorm, double* __restrict__ vbuf) {
  int b = blockIdx.x;
  int n = b / KC, c = b % KC;
  const float* f = feats + ((size_t)n * KC + c) * KHW;
  const float* s = sism + (size_t)n * KHW;
  const double* r = rnorm + (size_t)n * KHW;
  double acc = 0;
  for (int k = threadIdx.x; k < KHW; k += 256) acc += (double)f[k] * r[k] * (double)s[k];
  acc = blockReduceSumD(acc);
  if (threadIdx.x == 0) vbuf[b] = acc / (double)KHW;
}

// SIV[n,c] = vbuf[n,c] / max(||vbuf[n,:]||, eps)
__global__ void k_sivnorm(const double* __restrict__ vbuf, double* __restrict__ SIV) {
  int n = blockIdx.x;
  double v = vbuf[n * KC + threadIdx.x];
  double s2 = blockReduceSumD(v * v);
  double nn = sqrt(s2);
  if (nn < 1e-12) nn = 1e-12;
  SIV[n * KC + threadIdx.x] = v / nn;
}

// cm[n,m,k] = sum_c NF[n,c,k] * SIV[m,c]
__global__ void k_cm(const float* __restrict__ feats, const double* __restrict__ rnorm,
                     const double* __restrict__ SIV, double* __restrict__ cm) {
  __shared__ double sv[KN * KC];
  for (int i = threadIdx.x; i < KN * KC; i += 256) sv[i] = SIV[i];
  __syncthreads();
  int t = blockIdx.x * 256 + threadIdx.x;
  if (t >= KN * KHW) return;
  int n = t / KHW, k = t % KHW;
  const float* f = feats + (size_t)n * KC * KHW + k;
  double acc[KN];
  #pragma unroll
  for (int m = 0; m < KN; m++) acc[m] = 0.0;
  for (int c = 0; c < KC; ++c) {
    double fv = f[(size_t)c * KHW];
    #pragma unroll
    for (int m = 0; m < KN; m++) acc[m] += fv * sv[m * KC + c];
  }
  double r = rnorm[t];
  #pragma unroll
  for (int m = 0; m < KN; m++) cm[((size_t)n * KN + m) * KHW + k] = acc[m] * r;
}

// normalize cm rows over k (in place)
__global__ void k_cmnorm(double* __restrict__ cm) {
  double* row = cm + (size_t)blockIdx.x * KHW;
  double s = 0;
  for (int k = threadIdx.x; k < KHW; k += 256) { double v = row[k]; s += v * v; }
  s = blockReduceSumD(s);
  double nn = sqrt(s);
  if (nn < 1e-12) nn = 1e-12;
  double rn = 1.0 / nn;
  for (int k = threadIdx.x; k < KHW; k += 256) row[k] *= rn;
}

// S[n,k] = sum_m cm[n,m,k]
__global__ void k_s(const double* __restrict__ cm, double* __restrict__ S) {
  int t = blockIdx.x * 256 + threadIdx.x;
  if (t >= KN * KHW) return;
  int n = t / KHW, k = t % KHW;
  double s = 0;
  #pragma unroll
  for (int m = 0; m < KN; m++) s += cm[((size_t)n * KN + m) * KHW + k];
  S[t] = s;
}

// tbuf[n,m] = sum_k cm[n,m,k] * S[n,k]   ( = sum_p corr[n,m,p] )
__global__ void k_t(const double* __restrict__ cm, const double* __restrict__ S,
                    double* __restrict__ tbuf) {
  int b = blockIdx.x;
  int n = b / KN;
  const double* row = cm + (size_t)b * KHW;
  const double* Sv = S + (size_t)n * KHW;
  double acc = 0;
  for (int k = threadIdx.x; k < KHW; k += 256) acc += row[k] * Sv[k];
  acc = blockReduceSumD(acc);
  if (threadIdx.x == 0) tbuf[b] = acc;
}

// wv[n,:] = softmax_m(tbuf[n,:])
__global__ void k_wv(const double* __restrict__ tbuf, double* __restrict__ wv) {
  int n = threadIdx.x;
  if (n >= KN) return;
  double v[KN], mx = -1e300;
  #pragma unroll
  for (int m = 0; m < KN; m++) { v[m] = tbuf[n * KN + m]; mx = fmax(mx, v[m]); }
  double s = 0;
  #pragma unroll
  for (int m = 0; m < KN; m++) { v[m] = exp(v[m] - mx); s += v[m]; }
  #pragma unroll
  for (int m = 0; m < KN; m++) wv[n * KN + m] = v[m] / s;
}

// CSA[n,k] = sum_m cm[n,m,k]*wv[n,m]; then min-max normalize per n
__global__ void k_csa(const double* __restrict__ cm, const double* __restrict__ wv,
                      double* __restrict__ CSAd, float* __restrict__ CSAf) {
  __shared__ double w[KN];
  int n = blockIdx.x, tid = threadIdx.x;
  if (tid < KN) w[tid] = wv[n * KN + tid];
  __syncthreads();
  double v[7];
  int cnt = 0;
  double lmin = 1e300, lmax = -1e300;
  for (int k = tid; k < KHW; k += 256) {
    double a = 0;
    #pragma unroll
    for (int m = 0; m < KN; m++) a += cm[((size_t)n * KN + m) * KHW + k] * w[m];
    v[cnt++] = a;
    lmin = fmin(lmin, a);
    lmax = fmax(lmax, a);
  }
  double mn = blockReduceMinD(lmin);
  double mx = blockReduceMaxD(lmax);
  double inv = 1.0 / (mx - mn + 1e-12);
  cnt = 0;
  for (int k = tid; k < KHW; k += 256) {
    double nv = (v[cnt++] - mn) * inv;
    CSAd[(size_t)n * KHW + k] = nv;
    CSAf[(size_t)n * KHW + k] = (float)nv;
  }
}

// per-n descending argsort of CSA (bitonic, 2048 padded, fp64 keys)
__global__ void k_sort(const double* __restrict__ CSAd, int* __restrict__ idx) {
  __shared__ double key[2048];
  __shared__ int ki[2048];
  int n = blockIdx.x, tid = threadIdx.x;
  for (int i = tid; i < 2048; i += 256) {
    if (i < KHW) { key[i] = CSAd[(size_t)n * KHW + i]; ki[i] = i; }
    else { key[i] = -1e300; ki[i] = i; }
  }
  __syncthreads();
  for (int k = 2; k <= 2048; k <<= 1) {
    for (int j = k >> 1; j > 0; j >>= 1) {
      for (int t = tid; t < 1024; t += 256) {
        int i = ((t & ~(j - 1)) << 1) | (t & (j - 1));
        int p = i | j;
        double a = key[i], b = key[p];
        int ia = ki[i], ib = ki[p];
        bool desc = (i & k) == 0;
        bool sw = desc ? (a < b || (a == b && ia > ib))
                       : (a > b || (a == b && ia < ib));
        if (sw) { key[i] = b; key[p] = a; ki[i] = ib; ki[p] = ia; }
      }
      __syncthreads();
    }
  }
  for (int i = tid; i < KHW; i += 256) idx[n * KHW + i] = ki[i];
}

// ---------------- weight prep (bf16, conv-friendly layout) ----------------
__global__ void k_prepw1(const float* __restrict__ w1, bf16* __restrict__ w1p) {
  int t = blockIdx.x * 256 + threadIdx.x;
  if (t >= KOC * 9 * KHW) return;
  int o = t / (9 * KHW), r = t % (9 * KHW);
  int s = r / KHW, i = r % KHW;
  w1p[t] = __float2bfloat16(w1[(size_t)o * 9 * KHW + (size_t)i * 9 + s]);
}

__global__ void k_prepw2(const float* __restrict__ w2, bf16* __restrict__ w2p) {
  int t = blockIdx.x * 256 + threadIdx.x;
  if (t >= KOC * 9 * KOC) return;
  int o = t / (9 * KOC), r = t % (9 * KOC);
  int s = r / KOC, i = r % KOC;
  w2p[t] = __float2bfloat16(w2[(size_t)o * 9 * KOC + (size_t)i * 9 + s]);
}

__global__ void k_prepws(const float* __restrict__ ws, bf16* __restrict__ wsb) {
  int t = blockIdx.x * 256 + threadIdx.x;
  if (t >= KOC * KHW) return;
  wsb[t] = __float2bfloat16(ws[t]);
}

// ---------------- Gram GEMM: G[n,i,j] = sum_c NFT[n,i,c]*NFT[n,j,c] ----------------
__global__ __launch_bounds__(256) void k_gram(const short* __restrict__ NFT,
                                              bf16* __restrict__ Gbuf) {
  __shared__ short As[128][40];
  __shared__ short Bs[128][40];
  int n = blockIdx.z;
  int i0 = blockIdx.x * 128, j0 = blockIdx.y * 128;
  int tid = threadIdx.x, lane = tid & 63, wave = tid >> 6;
  int quad = lane >> 4, l15 = lane & 15;
  int wm = (wave >> 1) * 64, wn = (wave & 1) * 64;
  int ar = tid >> 2, ko = (tid & 3) * 8;
  const short* base = NFT + (size_t)n * KHW * KC;
  int a0r = min(i0 + ar, KHW - 1), a1r = min(i0 + ar + 64, KHW - 1);
  int b0r = min(j0 + ar, KHW - 1), b1r = min(j0 + ar + 64, KHW - 1);
  f32x4 acc[4][4] = {};
  for (int k0 = 0; k0 < KC; k0 += 32) {
    __syncthreads();
    *(float4*)&As[ar][ko]      = *(const float4*)&base[(size_t)a0r * KC + k0 + ko];
    *(float4*)&As[ar + 64][ko] = *(const float4*)&base[(size_t)a1r * KC + k0 + ko];
    *(float4*)&Bs[ar][ko]      = *(const float4*)&base[(size_t)b0r * KC + k0 + ko];
    *(float4*)&Bs[ar + 64][ko] = *(const float4*)&base[(size_t)b1r * KC + k0 + ko];
    __syncthreads();
    short8 a[4], b[4];
    #pragma unroll
    for (int t = 0; t < 4; t++) a[t] = *(const short8*)&As[wm + t * 16 + l15][quad * 8];
    #pragma unroll
    for (int t = 0; t < 4; t++) b[t] = *(const short8*)&Bs[wn + t * 16 + l15][quad * 8];
    #pragma unroll
    for (int ti = 0; ti < 4; ti++)
      #pragma unroll
      for (int tj = 0; tj < 4; tj++)
        acc[ti][tj] = __builtin_amdgcn_mfma_f32_16x16x32_bf16(a[ti], b[tj], acc[ti][tj], 0, 0, 0);
  }
  bf16* out = Gbuf + (size_t)n * KHW * KHW;
  for (int ti = 0; ti < 4; ti++) {
    int gr = i0 + wm + ti * 16 + quad * 4;
    for (int tj = 0; tj < 4; tj++) {
      int gc = j0 + wn + tj * 16 + l15;
      if (gc < KHW) {
        #pragma unroll
        for (int r = 0; r < 4; r++)
          if (gr + r < KHW)
            out[(size_t)(gr + r) * KHW + gc] = __float2bfloat16(acc[ti][tj][r]);
      }
    }
  }
}

// gather(argsort) + scale(CSA) + transpose + pad: xpadT[n, y+1, x+1, i] = G[n, idx[i], p]*CSA[n,p]
__global__ void k_xprep(const bf16* __restrict__ Gbuf, const int* __restrict__ idx,
                        const float* __restrict__ CSAf, bf16* __restrict__ xpadT) {
  __shared__ float T[32][33];
  int n = blockIdx.z, p0 = blockIdx.x * 32, i0 = blockIdx.y * 32;
  int tx = threadIdx.x, ty = threadIdx.y;
  const bf16* gb = Gbuf + (size_t)n * KHW * KHW;
  const int* id = idx + n * KHW;
  float csv = CSAf[n * KHW + p0 + tx];
  #pragma unroll
  for (int ii = 0; ii < 4; ii++) {
    int il = ty * 4 + ii;
    int src = id[i0 + il];
    T[il][tx] = __bfloat162float(gb[(size_t)src * KHW + p0 + tx]) * csv;
  }
  __syncthreads();
  bf16* xp = xpadT + (size_t)n * KPW * KPW * KHW;
  #pragma unroll
  for (int pc = 0; pc < 4; pc++) {
    int pl = ty * 4 + pc;
    int p = p0 + pl;
    int y = p / KH, x = p % KH;
    xp[((size_t)(y + 1) * KPW + (x + 1)) * KHW + i0 + tx] = __float2bfloat16(T[tx][pl]);
  }
}

// ---------------- conv1 (3x3, 1600->128) implicit GEMM, K split over dy ----------------
__global__ __launch_bounds__(256) void k_conv1(const short* __restrict__ w1p,
                                               const short* __restrict__ xpadT,
                                               float* __restrict__ hbuf) {
  __shared__ short As[128][40];
  __shared__ short Bs[128][40];
  int p0 = blockIdx.x * 128, dy = blockIdx.y, n = blockIdx.z;
  int tid = threadIdx.x, lane = tid & 63, wave = tid >> 6;
  int quad = lane >> 4, l15 = lane & 15;
  int wm = (wave >> 1) * 64, wn = (wave & 1) * 64;
  int ar = tid >> 2, ko = (tid & 3) * 8;
  const short* xb = xpadT + (size_t)n * KPW * KPW * KHW;
  int pr0 = min(p0 + ar, KHW - 1), pr1 = min(p0 + ar + 64, KHW - 1);
  int y0 = pr0 / KH, x0 = pr0 % KH;
  int y1 = pr1 / KH, x1 = pr1 % KH;
  f32x4 acc[4][4] = {};
  for (int dx = 0; dx < 3; ++dx) {
    const short* a0 = w1p + ((size_t)ar * 9 + dy * 3 + dx) * KHW + ko;
    const short* a1 = w1p + ((size_t)(ar + 64) * 9 + dy * 3 + dx) * KHW + ko;
    const short* b0 = xb + ((size_t)(y0 + dy) * KPW + (x0 + dx)) * KHW + ko;
    const short* b1 = xb + ((size_t)(y1 + dy) * KPW + (x1 + dx)) * KHW + ko;
    for (int k0 = 0; k0 < KHW; k0 += 32) {
      __syncthreads();
      *(float4*)&As[ar][ko]      = *(const float4*)&a0[k0];
      *(float4*)&As[ar + 64][ko] = *(const float4*)&a1[k0];
      *(float4*)&Bs[ar][ko]      = *(const float4*)&b0[k0];
      *(float4*)&Bs[ar + 64][ko] = *(const float4*)&b1[k0];
      __syncthreads();
      short8 a[4], b[4];
      #pragma unroll
      for (int t = 0; t < 4; t++) a[t] = *(const short8*)&As[wm + t * 16 + l15][quad * 8];
      #pragma unroll
      for (int t = 0; t < 4; t++) b[t] = *(const short8*)&Bs[wn + t * 16 + l15][quad * 8];
      #pragma unroll
      for (int ti = 0; ti < 4; ti++)
        #pragma unroll
        for (int tj = 0; tj < 4; tj++)
          acc[ti][tj] = __builtin_amdgcn_mfma_f32_16x16x32_bf16(a[ti], b[tj], acc[ti][tj], 0, 0, 0);
    }
  }
  float* hb = hbuf + (size_t)n * KOC * KHW;
  for (int ti = 0; ti < 4; ti++) {
    int go = wm + ti * 16 + quad * 4;
    for (int tj = 0; tj < 4; tj++) {
      int gp = p0 + wn + tj * 16 + l15;
      if (gp < KHW) {
        #pragma unroll
        for (int r = 0; r < 4; r++)
          atomicAdd(&hb[(size_t)(go + r) * KHW + gp], acc[ti][tj][r]);
      }
    }
  }
}

// ---------------- shortcut (1x1, 1600->128), K split in halves ----------------
__global__ __launch_bounds__(256) void k_scg(const short* __restrict__ wsb,
                                             const short* __restrict__ xpadT,
                                             float* __restrict__ scbuf) {
  __shared__ short As[128][40];
  __shared__ short Bs[128][40];
  int p0 = blockIdx.x * 128, kh = blockIdx.y, n = blockIdx.z;
  int tid = threadIdx.x, lane = tid & 63, wave = tid >> 6;
  int quad = lane >> 4, l15 = lane & 15;
  int wm = (wave >> 1) * 64, wn = (wave & 1) * 64;
  int ar = tid >> 2, ko = (tid & 3) * 8;
  const short* xb = xpadT + (size_t)n * KPW * KPW * KHW;
  int pr0 = min(p0 + ar, KHW - 1), pr1 = min(p0 + ar + 64, KHW - 1);
  int y0 = pr0 / KH, x0 = pr0 % KH;
  int y1 = pr1 / KH, x1 = pr1 % KH;
  const short* a0 = wsb + (size_t)ar * KHW + ko;
  const short* a1 = wsb + (size_t)(ar + 64) * KHW + ko;
  const short* b0 = xb + ((size_t)(y0 + 1) * KPW + (x0 + 1)) * KHW + ko;
  const short* b1 = xb + ((size_t)(y1 + 1) * KPW + (x1 + 1)) * KHW + ko;
  f32x4 acc[4][4] = {};
  for (int c = 0; c < 25; ++c) {
    int k0 = kh * 800 + c * 32;
    __syncthreads();
    *(float4*)&As[ar][ko]      = *(const float4*)&a0[k0];
    *(float4*)&As[ar + 64][ko] = *(const float4*)&a1[k0];
    *(float4*)&Bs[ar][ko]      = *(const float4*)&b0[k0];
    *(float4*)&Bs[ar + 64][ko] = *(const float4*)&b1[k0];
    __syncthreads();
    short8 a[4], b[4];
    #pragma unroll
    for (int t = 0; t < 4; t++) a[t] = *(const short8*)&As[wm + t * 16 + l15][quad * 8];
    #pragma unroll
    for (int t = 0; t < 4; t++) b[t] = *(const short8*)&Bs[wn + t * 16 + l15][quad * 8];
    #pragma unroll
    for (int ti = 0; ti < 4; ti++)
      #pragma unroll
      for (int tj = 0; tj < 4; tj++)
        acc[ti][tj] = __builtin_amdgcn_mfma_f32_16x16x32_bf16(a[ti], b[tj], acc[ti][tj], 0, 0, 0);
  }
  float* sb = scbuf + (size_t)n * KOC * KHW;
  for (int ti = 0; ti < 4; ti++) {
    int go = wm + ti * 16 + quad * 4;
    for (int tj = 0; tj < 4; tj++) {
      int gp = p0 + wn + tj * 16 + l15;
      if (gp < KHW) {
        #pragma unroll
        for (int r = 0; r < 4; r++)
          atomicAdd(&sb[(size_t)(go + r) * KHW + gp], acc[ti][tj][r]);
      }
    }
  }
}

// h prep: hpadT[n, y+1, x+1, o] = bf16(relu(hbuf[n,o,p] + b1[o]))
__global__ void k_hprep(const float* __restrict__ hbuf, const float* __restrict__ b1,
                        bf16* __restrict__ hpadT) {
  __shared__ float T[32][132];
  int n = blockIdx.y, p0 = blockIdx.x * 32;
  int tx = threadIdx.x, ty = threadIdx.y;
  const float* hb = hbuf + (size_t)n * KOC * KHW;
  #pragma unroll
  for (int oc = 0; oc < 16; oc++) {
    int o = oc * 8 + ty;
    T[tx][o] = fmaxf(hb[(size_t)o * KHW + p0 + tx] + b1[o], 0.0f);
  }
  __syncthreads();
  bf16* hp = hpadT + (size_t)n * KPW * KPW * KOC;
  #pragma unroll
  for (int pc = 0; pc < 4; pc++) {
    int pl = ty * 4 + pc;
    int p = p0 + pl;
    int y = p / KH, x = p % KH;
    bf16* row = hp + ((size_t)(y + 1) * KPW + (x + 1)) * KOC;
    #pragma unroll
    for (int u = 0; u < 4; u++) row[tx * 4 + u] = __float2bfloat16(T[pl][tx * 4 + u]);
  }
}

// ---------------- conv2 (3x3, 128->128), K split over dy ----------------
__global__ __launch_bounds__(256) void k_conv2(const short* __restrict__ w2p,
                                               const short* __restrict__ hpadT,
                                               float* __restrict__ acc2) {
  __shared__ short As[128][40];
  __shared__ short Bs[128][40];
  int p0 = blockIdx.x * 128, dy = blockIdx.y, n = blockIdx.z;
  int tid = threadIdx.x, lane = tid & 63, wave = tid >> 6;
  int quad = lane >> 4, l15 = lane & 15;
  int wm = (wave >> 1) * 64, wn = (wave & 1) * 64;
  int ar = tid >> 2, ko = (tid & 3) * 8;
  const short* hb = hpadT + (size_t)n * KPW * KPW * KOC;
  int pr0 = min(p0 + ar, KHW - 1), pr1 = min(p0 + ar + 64, KHW - 1);
  int y0 = pr0 / KH, x0 = pr0 % KH;
  int y1 = pr1 / KH, x1 = pr1 % KH;
  f32x4 acc[4][4] = {};
  for (int dx = 0; dx < 3; ++dx) {
    const short* a0 = w2p + (size_t)ar * 9 * KOC + (dy * 3 + dx) * KOC + ko;
    const short* a1 = w2p + (size_t)(ar + 64) * 9 * KOC + (dy * 3 + dx) * KOC + ko;
    const short* b0 = hb + ((size_t)(y0 + dy) * KPW + (x0 + dx)) * KOC + ko;
    const short* b1 = hb + ((size_t)(y1 + dy) * KPW + (x1 + dx)) * KOC + ko;
    for (int k0 = 0; k0 < KOC; k0 += 32) {
      __syncthreads();
      *(float4*)&As[ar][ko]      = *(const float4*)&a0[k0];
      *(float4*)&As[ar + 64][ko] = *(const float4*)&a1[k0];
      *(float4*)&Bs[ar][ko]      = *(const float4*)&b0[k0];
      *(float4*)&Bs[ar + 64][ko] = *(const float4*)&b1[k0];
      __syncthreads();
      short8 a[4], b[4];
      #pragma unroll
      for (int t = 0; t < 4; t++) a[t] = *(const short8*)&As[wm + t * 16 + l15][quad * 8];
      #pragma unroll
      for (int t = 0; t < 4; t++) b[t] = *(const short8*)&Bs[wn + t * 16 + l15][quad * 8];
      #pragma unroll
      for (int ti = 0; ti < 4; ti++)
        #pragma unroll
        for (int tj = 0; tj < 4; tj++)
          acc[ti][tj] = __builtin_amdgcn_mfma_f32_16x16x32_bf16(a[ti], b[tj], acc[ti][tj], 0, 0, 0);
    }
  }
  float* ab = acc2 + (size_t)n * KOC * KHW;
  for (int ti = 0; ti < 4; ti++) {
    int go = wm + ti * 16 + quad * 4;
    for (int tj = 0; tj < 4; tj++) {
      int gp = p0 + wn + tj * 16 + l15;
      if (gp < KHW) {
        #pragma unroll
        for (int r = 0; r < 4; r++)
          atomicAdd(&ab[(size_t)(go + r) * KHW + gp], acc[ti][tj][r]);
      }
    }
  }
}

// out = relu(conv2 + b2 + shortcut + bs)
__global__ void k_final(const float* __restrict__ acc2, const float* __restrict__ scbuf,
                        const float* __restrict__ b2, const float* __restrict__ bs,
                        float* __restrict__ out) {
  int t = blockIdx.x * 256 + threadIdx.x;
  if (t >= KN * KOC * KHW) return;
  int o = (t / KHW) % KOC;
  out[t] = fmaxf(acc2[t] + scbuf[t] + b2[o] + bs[o], 0.0f);
}

// ---------------- launch ----------------
extern "C" void kernel_launch(void* const* d_in, const int* in_sizes, int n_in,
                              void* d_out, int out_size, void* d_ws, size_t ws_size,
                              hipStream_t stream) {
  const float* feats = (const float*)d_in[0];
  const float* sisms = (const float*)d_in[1];
  const float* w1 = (const float*)d_in[2];
  const float* b1 = (const float*)d_in[3];
  const float* w2 = (const float*)d_in[4];
  const float* b2 = (const float*)d_in[5];
  const float* wsc = (const float*)d_in[6];
  const float* bsc = (const float*)d_in[7];
  float* out = (float*)d_out;

  char* w = (char*)d_ws;
  auto carve = [&](size_t bytes) -> void* {
    void* p = (void*)w;
    w += (bytes + 255) & ~(size_t)255;
    return p;
  };
  bf16* NFT   = (bf16*)carve((size_t)KN * KHW * KC * 2);          // 16.4 MB
  bf16* Gbuf  = (bf16*)carve((size_t)KN * KHW * KHW * 2);         // 51.2 MB (reused below)
  float* hbuf  = (float*)Gbuf;            // aliases Gbuf after it is consumed
  float* scbuf = hbuf + (size_t)KN * KOC * KHW;
  float* acc2  = scbuf + (size_t)KN * KOC * KHW;
  bf16* xpadT = (bf16*)carve((size_t)KN * KPW * KPW * KHW * 2);   // 56.4 MB
  bf16* hpadT = (bf16*)carve((size_t)KN * KPW * KPW * KOC * 2);   // 4.5 MB
  bf16* w1p   = (bf16*)carve((size_t)KOC * 9 * KHW * 2);
  bf16* w2p   = (bf16*)carve((size_t)KOC * 9 * KOC * 2);
  bf16* wsb   = (bf16*)carve((size_t)KOC * KHW * 2);
  double* rnorm = (double*)carve((size_t)KN * KHW * 8);
  double* vbuf  = (double*)carve((size_t)KN * KC * 8);
  double* SIV   = (double*)carve((size_t)KN * KC * 8);
  double* cm    = (double*)carve((size_t)KN * KN * KHW * 8);
  double* Sbuf  = (double*)carve((size_t)KN * KHW * 8);
  double* tbuf  = (double*)carve((size_t)KN * KN * 8);
  double* wvb   = (double*)carve((size_t)KN * KN * 8);
  double* CSAd  = (double*)carve((size_t)KN * KHW * 8);
  float* CSAf   = (float*)carve((size_t)KN * KHW * 4);
  int* idxb     = (int*)carve((size_t)KN * KHW * 4);

  hipMemsetAsync(xpadT, 0, (size_t)KN * KPW * KPW * KHW * 2, stream);
  hipMemsetAsync(hpadT, 0, (size_t)KN * KPW * KPW * KOC * 2, stream);

  k_rnorm<<<63, 256, 0, stream>>>(feats, rnorm);
  k_nft<<<dim3(50, 16, KN), dim3(32, 8), 0, stream>>>(feats, rnorm, NFT);
  k_sivpre<<<KN * KC, 256, 0, stream>>>(feats, sisms, rnorm, vbuf);
  k_sivnorm<<<KN, 512, 0, stream>>>(vbuf, SIV);
  k_cm<<<63, 256, 0, stream>>>(feats, rnorm, SIV, cm);
  k_cmnorm<<<KN * KN, 256, 0, stream>>>(cm);
  k_s<<<63, 256, 0, stream>>>(cm, Sbuf);
  k_t<<<KN * KN, 256, 0, stream>>>(cm, Sbuf, tbuf);
  k_wv<<<1, 64, 0, stream>>>(tbuf, wvb);
  k_csa<<<KN, 256, 0, stream>>>(cm, wvb, CSAd, CSAf);
  k_sort<<<KN, 256, 0, stream>>>(CSAd, idxb);

  k_prepw1<<<7200, 256, 0, stream>>>(w1, w1p);
  k_prepw2<<<576, 256, 0, stream>>>(w2, w2p);
  k_prepws<<<800, 256, 0, stream>>>(wsc, wsb);

  k_gram<<<dim3(13, 13, KN), 256, 0, stream>>>((const short*)NFT, Gbuf);
  k_xprep<<<dim3(50, 50, KN), dim3(32, 8), 0, stream>>>(Gbuf, idxb, CSAf, xpadT);

  // Gbuf is dead now; zero the aliased accumulators
  hipMemsetAsync(hbuf, 0, (size_t)3 * KN * KOC * KHW * 4, stream);

  k_conv1<<<dim3(13, 3, KN), 256, 0, stream>>>((const short*)w1p, (const short*)xpadT, hbuf);
  k_scg<<<dim3(13, 2, KN), 256, 0, stream>>>((const short*)wsb, (const short*)xpadT, scbuf);
  k_hprep<<<dim3(50, KN), dim3(32, 8), 0, stream>>>(hbuf, b1, hpadT);
  k_conv2<<<dim3(13, 3, KN), 256, 0, stream>>>((const short*)w2p, (const short*)hpadT, acc2);
  k_final<<<8000, 256, 0, stream>>>(acc2, scbuf, b2, bsc, out);
}